// Round 1
// baseline (133.171 us; speedup 1.0000x reference)
//
#include <hip/hip_runtime.h>
#include <math.h>

#define B_N   32
#define T_N   8192
#define D_N   256
#define CTX_N 128
#define TB    128
#define NBLK  (T_N / TB)        /* 64 t-chunks per batch */
#define NPART (B_N * NBLK)      /* 2048 partial blocks   */
#define XPITCH 264              /* bf16 elems per LDS row: 256 + 8 pad -> 528B rows */

typedef unsigned short u16;
typedef unsigned int   u32;
typedef __attribute__((ext_vector_type(8))) short bf16x8;
typedef __attribute__((ext_vector_type(8))) unsigned short u16x8;
typedef __attribute__((ext_vector_type(4))) float f32x4;

#define SH_BYTES (2 * TB * XPITCH * 2 + (128 * 3 + 8) * 4)

// ---------- helpers ----------
__device__ __forceinline__ u16 f2bf(float f) {          // RNE float->bf16
  u32 u = __float_as_uint(f);
  u32 r = (u + 0x7FFFu + ((u >> 16) & 1u)) >> 16;
  return (u16)r;
}
__device__ __forceinline__ float bf2f(u16 h) {
  return __uint_as_float(((u32)h) << 16);
}
__device__ __forceinline__ float fast_tanh(float x) {
  float e = __expf(2.0f * x);
  return (e - 1.0f) / (e + 1.0f);
}

// ---------- kernel 0: W (D x CTX, fp32) -> Wt (CTX x D, bf16) ----------
__global__ void prep_w(const float* __restrict__ W, u16* __restrict__ Wt) {
  int c = blockIdx.x;    // 0..127 (CTX)
  int d = threadIdx.x;   // 0..255 (D)
  Wt[c * D_N + d] = f2bf(W[d * CTX_N + c]);
}

// ---------- kernel 1: per (b, t-chunk) online-softmax partials ----------
__global__ __launch_bounds__(256)
void attn_partial(const float* __restrict__ X, const u16* __restrict__ Wt,
                  const float* __restrict__ u, float* __restrict__ part_o,
                  float* __restrict__ part_m, float* __restrict__ part_l) {
  extern __shared__ char smem[];
  u16*  Xl    = (u16*)smem;                         // [TB][XPITCH] bf16
  u16*  Wl    = (u16*)(smem + TB * XPITCH * 2);     // [CTX][XPITCH] bf16, Wl[n][k]=W[k][n]
  float* fbase = (float*)(smem + 2 * TB * XPITCH * 2);
  float* u_s   = fbase;          // [128]
  float* s_arr = fbase + 128;    // [128]
  float* p_arr = fbase + 256;    // [128]
  float* red   = fbase + 384;    // [8]

  const int tid = threadIdx.x;
  const int blk = blockIdx.x;          // 0..NPART-1
  const int b   = blk >> 6;            // / NBLK
  const int tc  = blk & (NBLK - 1);
  const float* Xblk = X + ((size_t)b * T_N + (size_t)tc * TB) * D_N;

  const int lane32 = tid & 31;
  const int rgrp   = tid >> 5;         // 0..7

  // ---- stage X chunk (fp32 -> bf16) ----
  #pragma unroll 4
  for (int pass = 0; pass < 16; ++pass) {
    int row = pass * 8 + rgrp;
    const float4* src = reinterpret_cast<const float4*>(Xblk + (size_t)row * D_N) + lane32 * 2;
    float4 v0 = src[0];
    float4 v1 = src[1];
    u16x8 pk;
    pk[0] = f2bf(v0.x); pk[1] = f2bf(v0.y); pk[2] = f2bf(v0.z); pk[3] = f2bf(v0.w);
    pk[4] = f2bf(v1.x); pk[5] = f2bf(v1.y); pk[6] = f2bf(v1.z); pk[7] = f2bf(v1.w);
    *reinterpret_cast<u16x8*>(&Xl[row * XPITCH + lane32 * 8]) = pk;
  }

  // ---- stage Wt (already bf16, n-major) ----
  #pragma unroll 4
  for (int pass = 0; pass < 16; ++pass) {
    int n = pass * 8 + rgrp;
    u16x8 w = *reinterpret_cast<const u16x8*>(Wt + n * D_N + lane32 * 8);
    *reinterpret_cast<u16x8*>(&Wl[n * XPITCH + lane32 * 8]) = w;
  }

  if (tid < CTX_N) u_s[tid] = u[tid];
  __syncthreads();

  // ---- MFMA: scores tile (128 rows) x (128 ctx) over K=256 ----
  const int wv  = tid >> 6;    // wave 0..3
  const int l   = tid & 63;
  const int l15 = l & 15;
  const int lg  = l >> 4;      // 0..3
  const int wr  = wv * 32;     // wave's row base

  f32x4 acc[2][8] = {};
  #pragma unroll
  for (int kk = 0; kk < 8; ++kk) {
    const int k0 = kk * 32 + lg * 8;
    bf16x8 a0 = *reinterpret_cast<const bf16x8*>(&Xl[(wr + l15) * XPITCH + k0]);
    bf16x8 a1 = *reinterpret_cast<const bf16x8*>(&Xl[(wr + 16 + l15) * XPITCH + k0]);
    #pragma unroll
    for (int ct = 0; ct < 8; ++ct) {
      bf16x8 bb = *reinterpret_cast<const bf16x8*>(&Wl[(ct * 16 + l15) * XPITCH + k0]);
      acc[0][ct] = __builtin_amdgcn_mfma_f32_16x16x32_bf16(a0, bb, acc[0][ct], 0, 0, 0);
      acc[1][ct] = __builtin_amdgcn_mfma_f32_16x16x32_bf16(a1, bb, acc[1][ct], 0, 0, 0);
    }
  }

  // ---- scores: s = sum_c u[c] * tanh(acc) ; per-row reduce over 16 lanes ----
  float uv[8];
  #pragma unroll
  for (int ct = 0; ct < 8; ++ct) uv[ct] = u_s[ct * 16 + l15];

  #pragma unroll
  for (int rt = 0; rt < 2; ++rt) {
    float sp[4] = {0.f, 0.f, 0.f, 0.f};
    #pragma unroll
    for (int ct = 0; ct < 8; ++ct) {
      #pragma unroll
      for (int r = 0; r < 4; ++r) sp[r] += uv[ct] * fast_tanh(acc[rt][ct][r]);
    }
    #pragma unroll
    for (int r = 0; r < 4; ++r) {
      float v = sp[r];
      v += __shfl_xor(v, 1);
      v += __shfl_xor(v, 2);
      v += __shfl_xor(v, 4);
      v += __shfl_xor(v, 8);
      if (l15 == 0) s_arr[wr + rt * 16 + lg * 4 + r] = v;
    }
  }
  __syncthreads();

  // ---- block max of the 128 scores ----
  float sv = s_arr[(wv & 1) * 64 + l];
  float mx = sv;
  #pragma unroll
  for (int off = 32; off; off >>= 1) mx = fmaxf(mx, __shfl_xor(mx, off));
  if (l == 0) red[wv] = mx;
  __syncthreads();
  const float m = fmaxf(fmaxf(red[0], red[1]), fmaxf(red[2], red[3]));

  // ---- p = exp(s - m), block sum ----
  float p = 0.f;
  if (wv < 2) {
    p = expf(sv - m);
    p_arr[wv * 64 + l] = p;
  }
  float ps = p;
  #pragma unroll
  for (int off = 32; off; off >>= 1) ps += __shfl_xor(ps, off);
  if (l == 0 && wv < 2) red[4 + wv] = ps;
  __syncthreads();
  const float lsum = red[4] + red[5];

  // ---- o_d = sum_t p_t * X[t][d]  (d = tid, from bf16 LDS copy) ----
  float o = 0.f;
  const int d = tid;
  #pragma unroll 8
  for (int t = 0; t < TB; ++t) {
    o += p_arr[t] * bf2f(Xl[t * XPITCH + d]);
  }
  part_o[(size_t)blk * D_N + d] = o;
  if (tid == 0) { part_m[blk] = m; part_l[blk] = lsum; }
}

// ---------- kernel 2: combine partials per batch ----------
__global__ __launch_bounds__(256)
void finalize(const float* __restrict__ part_o, const float* __restrict__ part_m,
              const float* __restrict__ part_l, float* __restrict__ out) {
  const int b = blockIdx.x;     // 0..31
  const int tid = threadIdx.x;  // 0..255 = d

  float mg = -1e30f;
  for (int i = 0; i < NBLK; ++i) mg = fmaxf(mg, part_m[b * NBLK + i]);

  float L = 0.f, o = 0.f;
  for (int i = 0; i < NBLK; ++i) {
    float sc = expf(part_m[b * NBLK + i] - mg);
    L += part_l[b * NBLK + i] * sc;
    o += part_o[((size_t)(b * NBLK + i)) * D_N + tid] * sc;
  }
  out[b * D_N + tid] = o / L;
}

// ---------- launch ----------
extern "C" void kernel_launch(void* const* d_in, const int* in_sizes, int n_in,
                              void* d_out, int out_size, void* d_ws, size_t ws_size,
                              hipStream_t stream) {
  const float* X = (const float*)d_in[0];
  const float* W = (const float*)d_in[1];
  const float* u = (const float*)d_in[2];
  float* out = (float*)d_out;

  // workspace layout
  u16*   Wt     = (u16*)d_ws;                                        // 64 KiB
  float* part_o = (float*)((char*)d_ws + 65536);                     // 2 MiB
  float* part_m = (float*)((char*)d_ws + 65536 + (size_t)NPART * D_N * 4);
  float* part_l = part_m + NPART;

  prep_w<<<CTX_N, D_N, 0, stream>>>(W, Wt);

  hipFuncSetAttribute(reinterpret_cast<const void*>(attn_partial),
                      hipFuncAttributeMaxDynamicSharedMemorySize, SH_BYTES);
  attn_partial<<<NPART, 256, SH_BYTES, stream>>>(X, Wt, u, part_o, part_m, part_l);

  finalize<<<B_N, 256, 0, stream>>>(part_o, part_m, part_l, out);
}

// Round 2
// 130.480 us; speedup vs baseline: 1.0206x; 1.0206x over previous
//
#include <hip/hip_runtime.h>
#include <math.h>
#include <stdint.h>

#define B_N   32
#define T_N   8192
#define D_N   256
#define CTX_N 128
#define TB    32                       /* rows per chunk  */
#define CPB   32                       /* chunks per block */
#define NBLOCKS 256                    /* 1 per CU         */
#define WPITCH 264                     /* bf16 elems, padded */

typedef unsigned short u16;
typedef unsigned int   u32;
typedef __attribute__((ext_vector_type(8))) short bf16x8;
typedef __attribute__((ext_vector_type(8))) unsigned short u16x8;
typedef __attribute__((ext_vector_type(4))) float f32x4;

/* LDS layout (bytes) */
#define X_BYTES   (2 * TB * D_N * 4)           /* 65536: double-buffered fp32 X */
#define W_OFF     X_BYTES
#define W_BYTES   (CTX_N * WPITCH * 2)         /* 67584 */
#define U_OFF     (W_OFF + W_BYTES)            /* 133120 */
#define SP_OFF    (U_OFF + 512)                /* 133632: s_part[2][32] */
#define P_OFF     (SP_OFF + 256)               /* 133888: p_arr[32]     */
#define SH_BYTES  (P_OFF + 128)                /* 134016 total          */

/* ---------- helpers ---------- */
__device__ __forceinline__ u16 f2bf(float f) {          /* RNE float->bf16 */
  u32 u = __float_as_uint(f);
  u32 r = (u + 0x7FFFu + ((u >> 16) & 1u)) >> 16;
  return (u16)r;
}
__device__ __forceinline__ float fast_tanh(float x) {
  float e = __expf(2.0f * x);
  return (e - 1.0f) * __builtin_amdgcn_rcpf(e + 1.0f);
}

typedef const __attribute__((address_space(1))) unsigned int glb_u32_t;
typedef __attribute__((address_space(3))) unsigned int lds_u32_t;

/* async 16B global->LDS DMA; LDS dest must be wave-uniform (HW adds lane*16) */
__device__ __forceinline__ void async_cp16(const void* g, void* l) {
  __builtin_amdgcn_global_load_lds((glb_u32_t*)g,
      (lds_u32_t*)(unsigned)(uintptr_t)l, 16, 0, 0);
}

/* ---------- kernel 0: W (D x CTX fp32) -> Wt (CTX x D bf16) ---------- */
__global__ void prep_w(const float* __restrict__ W, u16* __restrict__ Wt) {
  int c = blockIdx.x;    /* ctx  */
  int d = threadIdx.x;   /* dim  */
  Wt[c * D_N + d] = f2bf(W[d * CTX_N + c]);
}

/* ---------- kernel 1: pipelined per-block online-softmax attention ---------- */
__global__ __launch_bounds__(256, 1)
void attn_main(const float* __restrict__ X, const u16* __restrict__ Wt,
               const float* __restrict__ u,
               float* __restrict__ blk_o, float* __restrict__ blk_m,
               float* __restrict__ blk_l) {
  extern __shared__ char smem[];
  float* Xf   = (float*)smem;                   /* [2][TB][256] fp32, XOR-swizzled */
  u16*   Wl   = (u16*)(smem + W_OFF);           /* [128][WPITCH] bf16, Wl[n][k]    */
  float* u_s  = (float*)(smem + U_OFF);
  float* s_pt = (float*)(smem + SP_OFF);        /* [2][32] score partials          */
  float* p_ar = (float*)(smem + P_OFF);         /* [32]                            */

  const int tid = threadIdx.x;
  const int l   = tid & 63;
  const int w   = tid >> 6;
  const int l15 = l & 15;
  const int lg  = l >> 4;

  const int blk  = blockIdx.x;
  const int b    = blk >> 3;                    /* 8 blocks per batch      */
  const int rowB = (blk & 7) * (CPB * TB);      /* 1024 rows per block     */
  const float* Xbase = X + ((size_t)b * T_N + rowB) * D_N;

  /* ---- prologue: DMA chunk 0 into buf 0 (swizzled source, linear dest) ---- */
  {
    #pragma unroll
    for (int j = 0; j < 8; ++j) {
      int r = (w << 3) + j;                               /* wave-uniform row */
      unsigned so = ((unsigned)(l * 16)) ^ ((unsigned)((r & 7) << 5));
      async_cp16((const char*)(Xbase + (size_t)r * D_N) + so, smem + r * 1024);
    }
  }
  /* ---- stage W (bf16, n-major, padded) + u : once per block ---- */
  {
    const int lane32 = tid & 31, rg = tid >> 5;
    #pragma unroll 4
    for (int p = 0; p < 16; ++p) {
      int n = p * 8 + rg;
      u16x8 wv = *(const u16x8*)(Wt + n * D_N + lane32 * 8);
      *(u16x8*)(&Wl[n * WPITCH + lane32 * 8]) = wv;
    }
    if (tid < CTX_N) u_s[tid] = u[tid];
  }
  __syncthreads();            /* full drain: chunk0 + W visible */

  float m_run = -3.0e38f, l_run = 0.f, o_run = 0.f;

  const int rt = w & 1;                 /* row tile  (16 rows)   */
  const int ch = w >> 1;                /* ctx half  (64 cols)   */
  const int arow = (rt << 4) + l15;     /* A-fragment row        */
  const unsigned sA = (unsigned)((arow & 7) << 5);

  for (int c = 0; c < CPB; ++c) {
    const int cur = c & 1;
    const float* Xc = Xf + cur * (TB * D_N);

    /* issue next chunk's DMA, then counted wait for current chunk */
    if (c + 1 < CPB) {
      const float* src = Xbase + (size_t)(c + 1) * TB * D_N;
      char* dstb = smem + (cur ^ 1) * (TB * D_N * 4);
      #pragma unroll
      for (int j = 0; j < 8; ++j) {
        int r = (w << 3) + j;
        unsigned so = ((unsigned)(l * 16)) ^ ((unsigned)((r & 7) << 5));
        async_cp16((const char*)(src + (size_t)r * D_N) + so, dstb + r * 1024);
      }
      asm volatile("s_waitcnt vmcnt(8)" ::: "memory");  /* chunk c done; c+1 in flight */
    } else {
      asm volatile("s_waitcnt vmcnt(0)" ::: "memory");
    }
    __builtin_amdgcn_s_barrier();                       /* A: buf[cur] ready */
    asm volatile("" ::: "memory");

    /* ---- scores: (16 rows) x (64 ctx) per wave, K=256 ---- */
    f32x4 acc[4] = {};
    #pragma unroll
    for (int kk = 0; kk < 8; ++kk) {
      unsigned cb = ((unsigned)(kk * 128 + lg * 32)) ^ sA;   /* swizzled byte col */
      const float* ap = Xc + arow * D_N + (cb >> 2);
      float4 f0 = *(const float4*)ap;
      float4 f1 = *(const float4*)(ap + 4);
      bf16x8 a;
      a[0] = (short)f2bf(f0.x); a[1] = (short)f2bf(f0.y);
      a[2] = (short)f2bf(f0.z); a[3] = (short)f2bf(f0.w);
      a[4] = (short)f2bf(f1.x); a[5] = (short)f2bf(f1.y);
      a[6] = (short)f2bf(f1.z); a[7] = (short)f2bf(f1.w);
      const int k0 = kk * 32 + lg * 8;
      #pragma unroll
      for (int ct = 0; ct < 4; ++ct) {
        bf16x8 bb = *(const bf16x8*)(&Wl[((ch << 6) + (ct << 4) + l15) * WPITCH + k0]);
        acc[ct] = __builtin_amdgcn_mfma_f32_16x16x32_bf16(a, bb, acc[ct], 0, 0, 0);
      }
    }

    /* s = sum_c u[c]*tanh(.) ; C layout: col=ch*64+ct*16+l15, row=rt*16+lg*4+r */
    float sp[4] = {0.f, 0.f, 0.f, 0.f};
    #pragma unroll
    for (int ct = 0; ct < 4; ++ct) {
      float uc = u_s[(ch << 6) + (ct << 4) + l15];
      #pragma unroll
      for (int r = 0; r < 4; ++r) sp[r] += uc * fast_tanh(acc[ct][r]);
    }
    #pragma unroll
    for (int r = 0; r < 4; ++r) {
      float v = sp[r];
      v += __shfl_xor(v, 1); v += __shfl_xor(v, 2);
      v += __shfl_xor(v, 4); v += __shfl_xor(v, 8);
      if (l15 == 0) s_pt[(ch << 5) + (rt << 4) + (lg << 2) + r] = v;
    }
    asm volatile("s_waitcnt lgkmcnt(0)" ::: "memory");
    __builtin_amdgcn_s_barrier();                       /* B: s_pt ready */
    asm volatile("" ::: "memory");

    /* ---- softmax over 32 rows (redundant across waves, identical inputs) ---- */
    const int myrow = l & 31;
    float s = s_pt[myrow] + s_pt[32 + myrow];
    float mx = s;
    mx = fmaxf(mx, __shfl_xor(mx, 1));
    mx = fmaxf(mx, __shfl_xor(mx, 2));
    mx = fmaxf(mx, __shfl_xor(mx, 4));
    mx = fmaxf(mx, __shfl_xor(mx, 8));
    mx = fmaxf(mx, __shfl_xor(mx, 16));
    float p = __expf(s - mx);
    float ps = p;
    ps += __shfl_xor(ps, 1); ps += __shfl_xor(ps, 2);
    ps += __shfl_xor(ps, 4); ps += __shfl_xor(ps, 8); ps += __shfl_xor(ps, 16);
    if (tid < TB) p_ar[tid] = p;
    asm volatile("s_waitcnt lgkmcnt(0)" ::: "memory");
    __builtin_amdgcn_s_barrier();                       /* C: p_ar ready */
    asm volatile("" ::: "memory");

    /* ---- weighted sum (fp32 X from LDS) + online rescale ---- */
    float o = 0.f;
    #pragma unroll
    for (int t = 0; t < TB; ++t) {
      o += p_ar[t] * Xc[t * D_N + (tid ^ ((t & 7) << 3))];
    }
    float mnew = fmaxf(m_run, mx);
    float eo = __expf(m_run - mnew);
    float en = __expf(mx - mnew);
    o_run = o_run * eo + o * en;
    l_run = l_run * eo + ps * en;
    m_run = mnew;

    asm volatile("s_waitcnt lgkmcnt(0)" ::: "memory");
    __builtin_amdgcn_s_barrier();                       /* D: buf reads done */
    asm volatile("" ::: "memory");
  }

  blk_o[blk * D_N + tid] = o_run;
  if (tid == 0) { blk_m[blk] = m_run; blk_l[blk] = l_run; }
}

/* ---------- kernel 2: combine 8 block-partials per batch ---------- */
__global__ __launch_bounds__(256)
void finalize(const float* __restrict__ blk_o, const float* __restrict__ blk_m,
              const float* __restrict__ blk_l, float* __restrict__ out) {
  const int b = blockIdx.x, tid = threadIdx.x;
  float mg = -3.0e38f;
  #pragma unroll
  for (int i = 0; i < 8; ++i) mg = fmaxf(mg, blk_m[b * 8 + i]);
  float L = 0.f, o = 0.f;
  #pragma unroll
  for (int i = 0; i < 8; ++i) {
    float sc = __expf(blk_m[b * 8 + i] - mg);
    L += blk_l[b * 8 + i] * sc;
    o += blk_o[(size_t)(b * 8 + i) * D_N + tid] * sc;
  }
  out[b * D_N + tid] = o / L;
}

/* ---------- launch ---------- */
extern "C" void kernel_launch(void* const* d_in, const int* in_sizes, int n_in,
                              void* d_out, int out_size, void* d_ws, size_t ws_size,
                              hipStream_t stream) {
  const float* X = (const float*)d_in[0];
  const float* W = (const float*)d_in[1];
  const float* u = (const float*)d_in[2];
  float* out = (float*)d_out;

  u16*   Wt    = (u16*)d_ws;                                   /* 64 KiB  */
  float* blk_o = (float*)((char*)d_ws + 65536);                /* 256 KiB */
  float* blk_m = (float*)((char*)d_ws + 65536 + NBLOCKS * D_N * 4);
  float* blk_l = blk_m + NBLOCKS;

  prep_w<<<CTX_N, D_N, 0, stream>>>(W, Wt);

  hipFuncSetAttribute(reinterpret_cast<const void*>(attn_main),
                      hipFuncAttributeMaxDynamicSharedMemorySize, SH_BYTES);
  attn_main<<<NBLOCKS, 256, SH_BYTES, stream>>>(X, Wt, u, blk_o, blk_m, blk_l);

  finalize<<<B_N, 256, 0, stream>>>(blk_o, blk_m, blk_l, out);
}

// Round 3
// 78.614 us; speedup vs baseline: 1.6940x; 1.6598x over previous
//
#include <hip/hip_runtime.h>
#include <stdint.h>

#define B_N   32
#define T_N   8192
#define D_N   256
#define CTX_N 128
#define TB    32                      /* rows per chunk           */
#define CPB   4                       /* chunks per block         */
#define ROWS_PB (TB*CPB)              /* 128 rows per block       */
#define BLK_PER_B (T_N/ROWS_PB)       /* 64 blocks per batch      */
#define NBLOCKS (B_N*BLK_PER_B)       /* 2048                     */
#define XP    264                     /* bf16 pitch (528 B rows)  */

typedef unsigned short u16;
typedef unsigned int   u32;
typedef __attribute__((ext_vector_type(8))) short bf16x8;
typedef __attribute__((ext_vector_type(8))) unsigned short u16x8;
typedef __attribute__((ext_vector_type(4))) float f32x4;

__device__ __forceinline__ u16 f2bf(float f) {          /* RNE float->bf16 */
  u32 u = __float_as_uint(f);
  return (u16)((u + 0x7FFFu + ((u >> 16) & 1u)) >> 16);
}
__device__ __forceinline__ float bf2f(u16 h) {
  return __uint_as_float(((u32)h) << 16);
}
__device__ __forceinline__ float fast_tanh(float x) {
  float e = __expf(2.0f * x);
  return (e - 1.0f) * __builtin_amdgcn_rcpf(e + 1.0f);
}

/* ---------- kernel 0: W (D x CTX fp32) -> Wt (CTX x D bf16) ---------- */
__global__ void prep_w(const float* __restrict__ W, u16* __restrict__ Wt) {
  int c = blockIdx.x;    /* ctx */
  int d = threadIdx.x;   /* dim */
  Wt[c * D_N + d] = f2bf(W[d * CTX_N + c]);
}

/* ---------- kernel 1: fused scores+softmax+wsum, W in registers ---------- */
__global__ __launch_bounds__(512, 4)
void attn_main(const float* __restrict__ X, const u16* __restrict__ Wt,
               const float* __restrict__ u,
               float* __restrict__ blk_o, float* __restrict__ blk_l) {
  __shared__ u16   Xl[2][TB][XP];     /* 33792 B, double-buffered bf16 X  */
  __shared__ float s_part[8][TB];     /* per-wave score partials          */
  __shared__ float l_part[16];

  const int tid = threadIdx.x;
  const int w   = tid >> 6;           /* wave 0..7: owns ctx cols w*16..+15 */
  const int l   = tid & 63;
  const int l15 = l & 15;
  const int lg  = l >> 4;

  const int blk  = blockIdx.x;
  const int b    = blk >> 6;
  const int rowB = (blk & 63) * ROWS_PB;
  const float* Xbase = X + ((size_t)b * T_N + rowB) * D_N;

  /* ---- W^T fragments in registers: 8 x bf16x8 = 32 VGPRs ---- */
  bf16x8 bw[8];
  {
    const u16* wp = Wt + (w * 16 + l15) * D_N + lg * 8;
    #pragma unroll
    for (int kk = 0; kk < 8; ++kk) bw[kk] = *(const bf16x8*)(wp + kk * 32);
  }
  const float uc = u[w * 16 + l15];

  /* staging map: thread = (row srow, 16-float segment scol) */
  const int srow = tid >> 4;          /* 0..31 */
  const int scol = (tid & 15) << 4;   /* 0,16,...,240 */

  float4 pf0, pf1, pf2, pf3;          /* prefetch regs (chunk c+1) */
  {
    const float* sp = Xbase + (size_t)srow * D_N + scol;
    pf0 = ((const float4*)sp)[0]; pf1 = ((const float4*)sp)[1];
    pf2 = ((const float4*)sp)[2]; pf3 = ((const float4*)sp)[3];
  }

  /* wsum map: thread = (t-pair g, d8 slice) */
  const int g     = tid >> 5;         /* 0..15 -> rows 2g,2g+1 */
  const int slice = tid & 31;         /* d = slice*8 .. +8     */
  float o8[8] = {0,0,0,0,0,0,0,0};
  float l_run = 0.f;

  for (int c = 0; c < CPB; ++c) {
    const int cur = c & 1;

    /* ---- write staged chunk (fp32 regs -> bf16 LDS) ---- */
    u16x8 s0, s1;
    s0[0]=f2bf(pf0.x); s0[1]=f2bf(pf0.y); s0[2]=f2bf(pf0.z); s0[3]=f2bf(pf0.w);
    s0[4]=f2bf(pf1.x); s0[5]=f2bf(pf1.y); s0[6]=f2bf(pf1.z); s0[7]=f2bf(pf1.w);
    s1[0]=f2bf(pf2.x); s1[1]=f2bf(pf2.y); s1[2]=f2bf(pf2.z); s1[3]=f2bf(pf2.w);
    s1[4]=f2bf(pf3.x); s1[5]=f2bf(pf3.y); s1[6]=f2bf(pf3.z); s1[7]=f2bf(pf3.w);
    *(u16x8*)&Xl[cur][srow][scol]     = s0;
    *(u16x8*)&Xl[cur][srow][scol + 8] = s1;

    /* ---- issue next chunk's global loads (fly across barriers) ---- */
    if (c + 1 < CPB) {
      const float* sp = Xbase + ((size_t)(c + 1) * TB + srow) * D_N + scol;
      pf0 = ((const float4*)sp)[0]; pf1 = ((const float4*)sp)[1];
      pf2 = ((const float4*)sp)[2]; pf3 = ((const float4*)sp)[3];
    }

    asm volatile("s_waitcnt lgkmcnt(0)" ::: "memory");
    __builtin_amdgcn_s_barrier();                       /* A: buf[cur] ready */
    asm volatile("" ::: "memory");

    /* ---- scores: 32 rows x (this wave's 16 ctx cols), K=256 ---- */
    const u16* Xc = &Xl[cur][0][0];
    f32x4 acc0 = {0,0,0,0}, acc1 = {0,0,0,0};
    #pragma unroll
    for (int kk = 0; kk < 8; ++kk) {
      bf16x8 a0 = *(const bf16x8*)(Xc + l15 * XP + kk * 32 + lg * 8);
      bf16x8 a1 = *(const bf16x8*)(Xc + (16 + l15) * XP + kk * 32 + lg * 8);
      acc0 = __builtin_amdgcn_mfma_f32_16x16x32_bf16(a0, bw[kk], acc0, 0, 0, 0);
      acc1 = __builtin_amdgcn_mfma_f32_16x16x32_bf16(a1, bw[kk], acc1, 0, 0, 0);
    }
    /* partial s over this wave's cols; C layout: col=l15, row=lg*4+r (+16 for acc1) */
    #pragma unroll
    for (int r = 0; r < 4; ++r) {
      float v0 = uc * fast_tanh(acc0[r]);
      float v1 = uc * fast_tanh(acc1[r]);
      v0 += __shfl_xor(v0, 1); v0 += __shfl_xor(v0, 2);
      v0 += __shfl_xor(v0, 4); v0 += __shfl_xor(v0, 8);
      v1 += __shfl_xor(v1, 1); v1 += __shfl_xor(v1, 2);
      v1 += __shfl_xor(v1, 4); v1 += __shfl_xor(v1, 8);
      if (l15 == 0) {
        s_part[w][lg * 4 + r]      = v0;
        s_part[w][16 + lg * 4 + r] = v1;
      }
    }
    asm volatile("s_waitcnt lgkmcnt(0)" ::: "memory");
    __builtin_amdgcn_s_barrier();                       /* B: s_part ready */
    asm volatile("" ::: "memory");

    /* ---- p = exp(s) (bounded: |s| <= 6.4, no max needed), weighted sum ---- */
    float st0 = 0.f, st1 = 0.f;
    #pragma unroll
    for (int w2 = 0; w2 < 8; ++w2) {
      st0 += s_part[w2][2 * g];
      st1 += s_part[w2][2 * g + 1];
    }
    float p0 = __expf(st0), p1 = __expf(st1);
    if (slice == 0) l_run += p0 + p1;
    u16x8 x0 = *(const u16x8*)&Xl[cur][2 * g][slice * 8];
    u16x8 x1 = *(const u16x8*)&Xl[cur][2 * g + 1][slice * 8];
    #pragma unroll
    for (int j = 0; j < 8; ++j) o8[j] += p0 * bf2f(x0[j]) + p1 * bf2f(x1[j]);
    /* no trailing barrier: next iter writes the other buffer; barrier A of
       iter c+1 orders these reads before any write of iter c+2. */
  }

  /* ---- block combine: 16 t-groups -> one partial per d ---- */
  asm volatile("s_waitcnt lgkmcnt(0)" ::: "memory");
  __builtin_amdgcn_s_barrier();
  asm volatile("" ::: "memory");
  float* comb = (float*)&Xl[0][0][0];   /* 16 KiB, overlays buffer 0 */
  #pragma unroll
  for (int j = 0; j < 8; ++j) comb[g * 256 + slice * 8 + j] = o8[j];
  if (slice == 0) l_part[g] = l_run;
  asm volatile("s_waitcnt lgkmcnt(0)" ::: "memory");
  __builtin_amdgcn_s_barrier();
  asm volatile("" ::: "memory");
  if (tid < 256) {
    float o = 0.f;
    #pragma unroll
    for (int g2 = 0; g2 < 16; ++g2) o += comb[g2 * 256 + tid];
    blk_o[(size_t)blk * D_N + tid] = o;
  }
  if (tid == 0) {
    float L = 0.f;
    #pragma unroll
    for (int g2 = 0; g2 < 16; ++g2) L += l_part[g2];
    blk_l[blk] = L;
  }
}

/* ---------- kernel 2: combine 64 block-partials per batch ---------- */
__global__ __launch_bounds__(256)
void finalize(const float* __restrict__ blk_o, const float* __restrict__ blk_l,
              float* __restrict__ out) {
  const int b = blockIdx.x, d = threadIdx.x;
  float o = 0.f, L = 0.f;
  for (int i = 0; i < BLK_PER_B; ++i) {
    o += blk_o[(size_t)(b * BLK_PER_B + i) * D_N + d];
    L += blk_l[b * BLK_PER_B + i];
  }
  out[b * D_N + d] = o / L;
}

/* ---------- launch ---------- */
extern "C" void kernel_launch(void* const* d_in, const int* in_sizes, int n_in,
                              void* d_out, int out_size, void* d_ws, size_t ws_size,
                              hipStream_t stream) {
  const float* X = (const float*)d_in[0];
  const float* W = (const float*)d_in[1];
  const float* u = (const float*)d_in[2];
  float* out = (float*)d_out;

  u16*   Wt    = (u16*)d_ws;                                        /* 64 KiB */
  float* blk_o = (float*)((char*)d_ws + 65536);                     /* 2 MiB  */
  float* blk_l = (float*)((char*)d_ws + 65536 + (size_t)NBLOCKS * D_N * 4);

  prep_w<<<CTX_N, D_N, 0, stream>>>(W, Wt);
  attn_main<<<NBLOCKS, 512, 0, stream>>>(X, Wt, u, blk_o, blk_l);
  finalize<<<B_N, 256, 0, stream>>>(blk_o, blk_l, out);
}